// Round 5
// baseline (746.855 us; speedup 1.0000x reference)
//
#include <hip/hip_runtime.h>

#define NPTS 100000
#define CC   64
#define KK   27
#define TOT  (KK * NPTS)        // 2,700,000 edges
#define SEGS (NPTS * KK)        // 2,700,000 (k,dst) segments, k-major
#define EPSBN 1e-5f
#define MT   128                // output rows per conv block

#define NRANGE 16               // dst ranges per slice
#define RSIZE  (NPTS / NRANGE)  // 6250 dsts per range
#define CAP    6784             // LDS edge-list capacity (mean 6250 + ~7 sigma)
#define CHUNK  12500            // edges per k_rhist block (divides NPTS)

typedef float          f32x4  __attribute__((ext_vector_type(4)));
typedef short          bf16x8 __attribute__((ext_vector_type(8)));
typedef unsigned int   u32x4  __attribute__((ext_vector_type(4)));
typedef unsigned short u16x4  __attribute__((ext_vector_type(4)));
typedef int            i32x4  __attribute__((ext_vector_type(4)));

__device__ __forceinline__ unsigned short f2bf(float f) {
    unsigned int u = __float_as_uint(f);
    u = (u + 0x7fffu + ((u >> 16) & 1u)) >> 16;
    return (unsigned short)u;
}

// ---------------- prep: x -> bf16 ----------------
__global__ void k_convert_x(const float* __restrict__ x, unsigned short* __restrict__ xb) {
    int id = blockIdx.x * 256 + threadIdx.x;
    f32x4 v = ((const f32x4*)x)[id];
    u16x4 o;
#pragma unroll
    for (int j = 0; j < 4; ++j) o[j] = f2bf(v[j]);
    ((u16x4*)xb)[id] = o;
}

// ---------------- prep: W[k][cin][cout] fp32 -> Wt[k][cout][cin] bf16 ----------------
__global__ void k_prep_w(const float* __restrict__ W1, const float* __restrict__ W2,
                         unsigned short* __restrict__ Wt1, unsigned short* __restrict__ Wt2) {
    int id = blockIdx.x * 256 + threadIdx.x;
    int which = id / (KK * CC * CC);
    int r = id % (KK * CC * CC);
    int k = r / (CC * CC);
    int rem = r % (CC * CC);
    int cin = rem / CC, cout = rem % CC;
    const float* W = which ? W2 : W1;
    unsigned short* Wt = which ? Wt2 : Wt1;
    Wt[k * CC * CC + cout * CC + cin] = f2bf(W[r]);
}

// ---------------- CSR build: per-(k,range) counting sort ----------------
__global__ void k_rhist(const int* __restrict__ out_idx, int* __restrict__ rcnt) {
    __shared__ int rc[NRANGE];
    int t = threadIdx.x;
    if (t < NRANGE) rc[t] = 0;
    __syncthreads();
    int j0 = blockIdx.x * CHUNK;
    int k = j0 / NPTS;
    const i32x4* src = (const i32x4*)(out_idx + j0);
    for (int ii = t; ii < CHUNK / 4; ii += 256) {
        i32x4 d = src[ii];
#pragma unroll
        for (int q = 0; q < 4; ++q) atomicAdd(&rc[d[q] / RSIZE], 1);
    }
    __syncthreads();
    if (t < NRANGE) atomicAdd(&rcnt[k * NRANGE + t], rc[t]);
}

__global__ void k_rscan(const int* __restrict__ rcnt, int* __restrict__ rbase,
                        int* __restrict__ offs) {
    int t = threadIdx.x;
    if (t < KK) {
        int run = t * NPTS;
        for (int r = 0; r < NRANGE; ++r) {
            rbase[t * NRANGE + r] = run;
            run += rcnt[t * NRANGE + r];
        }
    }
    if (t == 0) offs[SEGS] = TOT;
}

__global__ __launch_bounds__(256) void k_sort(
    const int* __restrict__ out_idx, const int* __restrict__ in_idx,
    const int* __restrict__ rbase,
    int* __restrict__ offs, int* __restrict__ entries) {
    __shared__ int cnt[RSIZE];            // 25 KB
    __shared__ unsigned list[CAP];        // 26.5 KB
    __shared__ int psum[256];
    __shared__ int nlist;

    const int t = threadIdx.x;
    const int lane = t & 63;
    const int k = blockIdx.x / NRANGE;
    const int r = blockIdx.x % NRANGE;
    const int dlo = r * RSIZE;

    for (int i = t; i < RSIZE; i += 256) cnt[i] = 0;
    if (t == 0) nlist = 0;
    __syncthreads();

    // single coalesced pass; wave-ballot aggregated append
    const i32x4* dsrc = (const i32x4*)(out_idx + k * NPTS);
    const i32x4* ssrc = (const i32x4*)(in_idx + k * NPTS);
    for (int ii = t; ii < NPTS / 4; ii += 256) {
        i32x4 d4 = dsrc[ii];
        i32x4 s4 = ssrc[ii];
#pragma unroll
        for (int q = 0; q < 4; ++q) {
            int dloc = d4[q] - dlo;
            bool pred = (unsigned)dloc < (unsigned)RSIZE;
            unsigned long long m = __ballot(pred);
            if (m) {
                int leader = __ffsll((unsigned long long)m) - 1;
                int cm = __popcll(m);
                int base = 0;
                if (lane == leader) base = atomicAdd(&nlist, cm);
                base = __shfl(base, leader);
                if (pred) {
                    int pos = base + __popcll(m & ((1ull << lane) - 1ull));
                    if (pos < CAP) list[pos] = ((unsigned)dloc << 17) | (unsigned)s4[q];
                    atomicAdd(&cnt[dloc], 1);
                }
            }
        }
    }
    __syncthreads();

    // two-pass chunked exclusive scan (25 elems/thread)
    const int TS = (RSIZE + 255) / 256;   // 25
    int s = 0;
#pragma unroll
    for (int q = 0; q < TS; ++q) {
        int i = t * TS + q;
        if (i < RSIZE) s += cnt[i];
    }
    psum[t] = s;
    __syncthreads();
    for (int o = 1; o < 256; o <<= 1) {
        int pv = (t >= o) ? psum[t - o] : 0;
        __syncthreads();
        psum[t] += pv;
        __syncthreads();
    }
    int run = rbase[blockIdx.x] + (t ? psum[t - 1] : 0);
#pragma unroll
    for (int q = 0; q < TS; ++q) {
        int i = t * TS + q;
        if (i < RSIZE) {
            int v = cnt[i];
            offs[k * NPTS + dlo + i] = run;
            cnt[i] = run;
            run += v;
        }
    }
    __syncthreads();

    // placement into this block's private contiguous entries region
    int nl = nlist < CAP ? nlist : CAP;
    for (int i = t; i < nl; i += 256) {
        unsigned u = list[i];
        int dloc = u >> 17;
        int src = u & 0x1FFFF;
        int p = atomicAdd(&cnt[dloc], 1);
        entries[p] = src;
    }
}

// ---------------- conv v3: per-wave barrier-free 4-stage pipeline ----------------
__global__ __launch_bounds__(256, 3) void k_conv(
    const unsigned short* __restrict__ xb,    // [N][64] bf16
    const unsigned short* __restrict__ Wt,    // [27][cout=64][cin=64] bf16
    const int* __restrict__ offs,             // [SEGS+1], k-major
    const int* __restrict__ entries,          // [TOT] src indices
    float* __restrict__ y)                    // [N][64] fp32
{
    __shared__ unsigned seginfo[KK * MT];     // 13824 B: (gstart<<6)|cnt
    __shared__ int wmax[4][KK];               // per-wave max count per k

    const int tid  = threadIdx.x;
    const int lane = tid & 63;
    const int wave = tid >> 6;
    const int quad = lane >> 4;
    const int l16  = lane & 15;
    const int i0   = blockIdx.x * MT;

    if (tid < 4 * KK) wmax[tid / KK][tid % KK] = 1;
    __syncthreads();
    for (int idx = tid; idx < KK * MT; idx += 256) {
        int k = idx >> 7;
        int r = idx & 127;
        int gi = i0 + r;
        unsigned pack = 0;
        int c = 0;
        if (gi < NPTS) {
            int seg = k * NPTS + gi;
            int b = offs[seg];
            c = offs[seg + 1] - b;
            c = c > 63 ? 63 : c;
            pack = ((unsigned)b << 6) | (unsigned)c;
        }
        seginfo[idx] = pack;
        if (c > 1) atomicMax(&wmax[r >> 5][k], c);
    }
    __syncthreads();
    // ---- everything below is per-wave; no barriers ----

    int Tw = 0;
    for (int k = 0; k < KK; ++k) Tw += wmax[wave][k];

    const int wrow0 = wave * 32 + l16;
    const int wrow1 = wrow0 + 16;

    auto adv = [&](int& k, int& j) {
        j++;
        if (j >= wmax[wave][k] && k < KK - 1) { j = 0; k++; }
        // at k==KK-1, j grows past wmax -> predicates go false (dead zone)
    };

    int ka = 0, ja = 0;
    int kb = ka, jb = ja; adv(kb, jb);
    int kc = kb, jc = jb; adv(kc, jc);
    int kd = kc, jd = jc; adv(kd, jd);

    const bf16x8 z = {0, 0, 0, 0, 0, 0, 0, 0};
    bf16x8 cfr00 = z, cfr01 = z, cfr10 = z, cfr11 = z;
    bf16x8 bfr[4][2], nbfr[4][2];

    // warm-up: seginfo for a,b,c; entries for a,b; frags for a; B for k=0
    unsigned sa0 = seginfo[ka * MT + wrow0], sa1 = seginfo[ka * MT + wrow1];
    unsigned sb0 = seginfo[kb * MT + wrow0], sb1 = seginfo[kb * MT + wrow1];
    unsigned sc0 = seginfo[kc * MT + wrow0], sc1 = seginfo[kc * MT + wrow1];
    int ea0 = entries[min((int)(sa0 >> 6) + ja, TOT - 1)];
    int ea1 = entries[min((int)(sa1 >> 6) + ja, TOT - 1)];
    int eb0 = entries[min((int)(sb0 >> 6) + jb, TOT - 1)];
    int eb1 = entries[min((int)(sb1 >> 6) + jb, TOT - 1)];
    int cb0 = (int)(sb0 & 63), cb1 = (int)(sb1 & 63);
    if (ja < (int)(sa0 & 63)) {
        const unsigned short* p = xb + (long)ea0 * CC + quad * 8;
        cfr00 = *(const bf16x8*)p;
        cfr01 = *(const bf16x8*)(p + 32);
    }
    if (ja < (int)(sa1 & 63)) {
        const unsigned short* p = xb + (long)ea1 * CC + quad * 8;
        cfr10 = *(const bf16x8*)p;
        cfr11 = *(const bf16x8*)(p + 32);
    }
#pragma unroll
    for (int nt = 0; nt < 4; ++nt)
#pragma unroll
        for (int kt = 0; kt < 2; ++kt)
            bfr[nt][kt] = *(const bf16x8*)(Wt + (nt * 16 + l16) * CC + kt * 32 + quad * 8);

    f32x4 acc[2][4];
#pragma unroll
    for (int mt = 0; mt < 2; ++mt)
#pragma unroll
        for (int nt = 0; nt < 4; ++nt) acc[mt][nt] = (f32x4){0.f, 0.f, 0.f, 0.f};

    for (int t = 0; t < Tw; ++t) {
        // stage1: seginfo prefetch for cursor d
        unsigned nd0 = seginfo[kd * MT + wrow0];
        unsigned nd1 = seginfo[kd * MT + wrow1];
        // stage2: entries loads for cursor c
        int ec0 = entries[min((int)(sc0 >> 6) + jc, TOT - 1)];
        int ec1 = entries[min((int)(sc1 >> 6) + jc, TOT - 1)];
        // stage3: A-frag loads for cursor b
        bf16x8 nfr00 = z, nfr01 = z, nfr10 = z, nfr11 = z;
        if (jb < cb0) {
            const unsigned short* p = xb + (long)eb0 * CC + quad * 8;
            nfr00 = *(const bf16x8*)p;
            nfr01 = *(const bf16x8*)(p + 32);
        }
        if (jb < cb1) {
            const unsigned short* p = xb + (long)eb1 * CC + quad * 8;
            nfr10 = *(const bf16x8*)p;
            nfr11 = *(const bf16x8*)(p + 32);
        }
        // stage4: B prefetch for a's next k (once per k)
        if (ja == 0) {
            int kn = ka + 1 < KK ? ka + 1 : KK - 1;
            const unsigned short* wp = Wt + kn * CC * CC;
#pragma unroll
            for (int nt = 0; nt < 4; ++nt)
#pragma unroll
                for (int kt = 0; kt < 2; ++kt)
                    nbfr[nt][kt] = *(const bf16x8*)(wp + (nt * 16 + l16) * CC +
                                                    kt * 32 + quad * 8);
        }
        // stage5: MFMA for cursor a
#pragma unroll
        for (int nt = 0; nt < 4; ++nt) {
            acc[0][nt] = __builtin_amdgcn_mfma_f32_16x16x32_bf16(cfr00, bfr[nt][0], acc[0][nt], 0, 0, 0);
            acc[0][nt] = __builtin_amdgcn_mfma_f32_16x16x32_bf16(cfr01, bfr[nt][1], acc[0][nt], 0, 0, 0);
            acc[1][nt] = __builtin_amdgcn_mfma_f32_16x16x32_bf16(cfr10, bfr[nt][0], acc[1][nt], 0, 0, 0);
            acc[1][nt] = __builtin_amdgcn_mfma_f32_16x16x32_bf16(cfr11, bfr[nt][1], acc[1][nt], 0, 0, 0);
        }
        // stage6: rotate
        cfr00 = nfr00; cfr01 = nfr01; cfr10 = nfr10; cfr11 = nfr11;
        int kaold = ka;
        ka = kb; ja = jb;
        kb = kc; jb = jc;
        kc = kd; jc = jd;
        eb0 = ec0; eb1 = ec1;
        cb0 = (int)(sc0 & 63); cb1 = (int)(sc1 & 63);
        sc0 = nd0; sc1 = nd1;
        adv(kd, jd);
        if (ka != kaold) {
#pragma unroll
            for (int nt = 0; nt < 4; ++nt)
#pragma unroll
                for (int kt = 0; kt < 2; ++kt) bfr[nt][kt] = nbfr[nt][kt];
        }
    }

    // epilogue: D row = quad*4 + rr, col = l16 (within each 16x16 tile)
#pragma unroll
    for (int mt = 0; mt < 2; ++mt) {
        int rbase_ = i0 + wave * 32 + mt * 16 + quad * 4;
#pragma unroll
        for (int nt = 0; nt < 4; ++nt) {
            int col = nt * 16 + l16;
#pragma unroll
            for (int rr = 0; rr < 4; ++rr) {
                int gr = rbase_ + rr;
                if (gr < NPTS) y[(long)gr * CC + col] = acc[mt][nt][rr];
            }
        }
    }
}

// ---------------- BN ----------------
__global__ void k_bn_stats(const float* __restrict__ y, float* __restrict__ sums) {
    __shared__ float s1[256], s2[256];
    int t = threadIdx.x;
    int c = t & 63, g = t >> 6;
    float a = 0.f, b = 0.f;
    for (int i = blockIdx.x * 4 + g; i < NPTS; i += gridDim.x * 4) {
        float v = y[(long)i * CC + c];
        a += v; b += v * v;
    }
    s1[t] = a; s2[t] = b;
    __syncthreads();
    if (t < 64) {
        a = s1[t] + s1[t + 64] + s1[t + 128] + s1[t + 192];
        b = s2[t] + s2[t + 64] + s2[t + 128] + s2[t + 192];
        atomicAdd(&sums[t], a);
        atomicAdd(&sums[t + 64], b);
    }
}

__global__ void k_bn_fin(const float* __restrict__ sums, const float* __restrict__ gamma,
                         const float* __restrict__ beta, float* __restrict__ sb) {
    int c = threadIdx.x;   // 64 threads
    float mu  = sums[c] * (1.0f / NPTS);
    float var = sums[c + 64] * (1.0f / NPTS) - mu * mu;
    float s = gamma[c] * rsqrtf(var + EPSBN);
    sb[c] = s;
    sb[c + 64] = beta[c] - mu * s;
}

// a1 = bf16(relu(y*s + b))
__global__ void k_apply(const float* __restrict__ y, const float* __restrict__ sb,
                        unsigned short* __restrict__ ab) {
    int id = blockIdx.x * 256 + threadIdx.x;
    f32x4 v = ((const f32x4*)y)[id];
    int c0 = (id * 4) & 63;
    u16x4 o;
#pragma unroll
    for (int j = 0; j < 4; ++j) {
        float t = fmaxf(v[j] * sb[c0 + j] + sb[64 + c0 + j], 0.f);
        o[j] = f2bf(t);
    }
    ((u16x4*)ab)[id] = o;
}

// out = relu(y*s + b + x)
__global__ void k_final(const float* __restrict__ y, const float* __restrict__ x,
                        const float* __restrict__ sb, float* __restrict__ out) {
    int id = blockIdx.x * 256 + threadIdx.x;
    f32x4 v  = ((const f32x4*)y)[id];
    f32x4 xv = ((const f32x4*)x)[id];
    int c0 = (id * 4) & 63;
    f32x4 o;
#pragma unroll
    for (int j = 0; j < 4; ++j)
        o[j] = fmaxf(v[j] * sb[c0 + j] + sb[64 + c0 + j] + xv[j], 0.f);
    ((f32x4*)out)[id] = o;
}

extern "C" void kernel_launch(void* const* d_in, const int* in_sizes, int n_in,
                              void* d_out, int out_size, void* d_ws, size_t ws_size,
                              hipStream_t stream) {
    const float* x      = (const float*)d_in[0];
    // d_in[1] = norm_points (unused by the reference math)
    const float* W1     = (const float*)d_in[2];
    const float* gamma1 = (const float*)d_in[3];
    const float* beta1  = (const float*)d_in[4];
    const float* W2     = (const float*)d_in[5];
    const float* gamma2 = (const float*)d_in[6];
    const float* beta2  = (const float*)d_in[7];
    const int* in_idx   = (const int*)d_in[8];
    const int* out_idx  = (const int*)d_in[9];
    float* out = (float*)d_out;

    char* w = (char*)d_ws;
    size_t off = 0;
    auto alloc = [&](size_t bytes) -> char* {
        off = (off + 255) & ~(size_t)255;
        char* p = w + off;
        off += bytes;
        return p;
    };
    int*   rcnt    = (int*)  alloc((size_t)KK * NRANGE * 4);
    float* sums    = (float*)alloc(256 * 4);            // [0:128) layer1, [128:256) layer2
    int*   rbase   = (int*)  alloc((size_t)KK * NRANGE * 4);
    float* sb      = (float*)alloc(256 * 4);
    int*   offs    = (int*)  alloc(((size_t)SEGS + 1) * 4);
    int*   entries = (int*)  alloc((size_t)SEGS * 4);
    unsigned short* xbf = (unsigned short*)alloc((size_t)NPTS * CC * 2);
    unsigned short* Wt1 = (unsigned short*)alloc((size_t)KK * CC * CC * 2);
    unsigned short* Wt2 = (unsigned short*)alloc((size_t)KK * CC * CC * 2);
    float* y = (float*)alloc((size_t)NPTS * CC * 4);

    // zero rcnt + sums (contiguous; covers alignment gap)
    size_t zlen = (size_t)((char*)(sums + 256) - (char*)rcnt);
    hipMemsetAsync(rcnt, 0, zlen, stream);

    k_convert_x<<<NPTS * CC / 1024, 256, 0, stream>>>(x, xbf);
    k_prep_w<<<(2 * KK * CC * CC) / 256, 256, 0, stream>>>(W1, W2, Wt1, Wt2);
    k_rhist<<<TOT / CHUNK, 256, 0, stream>>>(out_idx, rcnt);
    k_rscan<<<1, 64, 0, stream>>>(rcnt, rbase, offs);
    k_sort<<<KK * NRANGE, 256, 0, stream>>>(out_idx, in_idx, rbase, offs, entries);

    const int CONVB = (NPTS + MT - 1) / MT;
    k_conv<<<CONVB, 256, 0, stream>>>(xbf, Wt1, offs, entries, y);
    k_bn_stats<<<256, 256, 0, stream>>>(y, sums);
    k_bn_fin<<<1, 64, 0, stream>>>(sums, gamma1, beta1, sb);
    k_apply<<<NPTS * CC / 1024, 256, 0, stream>>>(y, sb, xbf);   // a1 overwrites xbf
    k_conv<<<CONVB, 256, 0, stream>>>(xbf, Wt2, offs, entries, y);
    k_bn_stats<<<256, 256, 0, stream>>>(y, sums + 128);
    k_bn_fin<<<1, 64, 0, stream>>>(sums + 128, gamma2, beta2, sb + 128);
    k_final<<<NPTS * CC / 1024, 256, 0, stream>>>(y, x, sb + 128, out);
}